// Round 2
// baseline (6661.755 us; speedup 1.0000x reference)
//
#include <hip/hip_runtime.h>
#include <hip/hip_bf16.h>
#include <math.h>

typedef __hip_bfloat16 bf16;

#define NB 128    // batch
#define NT 24     // time steps
#define NE 512    // embed dim
#define NH 512    // hidden dim
#define NR 512    // factor rank
#define NTAG 400  // tags
#define NV 20000  // vocab

__device__ __forceinline__ float b2f(bf16 x) { return __bfloat162float(x); }
__device__ __forceinline__ float ldin(const void* p, long i, int f32) {
    return f32 ? ((const float*)p)[i] : b2f(((const bf16*)p)[i]);
}

// Detect input dtype: scan emb as u16; fp32 data's low halves produce
// exponent-all-ones bf16 patterns at p~1/256; true bf16 (scale 0.02) never does.
__global__ __launch_bounds__(256) void k_detect(const void* emb, int* flag) {
    __shared__ int cnt;
    if (threadIdx.x == 0) cnt = 0;
    __syncthreads();
    const unsigned short* p = (const unsigned short*)emb;
    int local = 0;
    for (int i = threadIdx.x; i < 65536; i += 256) {
        unsigned short v = p[i];
        if ((v & 0x7F80) == 0x7F80) local++;
    }
    atomicAdd(&cnt, local);
    __syncthreads();
    if (threadIdx.x == 0) *flag = (cnt > 4) ? 1 : 0;
}

// temp2[g][b][r] = sum_t s[b][t]*Wb[g][t][r] ; temp5 likewise with Ub
__global__ __launch_bounds__(256) void k_tags(const void* __restrict__ s,
        const void* __restrict__ Wb, const void* __restrict__ Ub,
        const int* __restrict__ flagp, float* __restrict__ temp2, float* __restrict__ temp5) {
    int f32 = *flagp;
    int idx = blockIdx.x * 256 + threadIdx.x;      // over 4*NB*NR
    int r = idx & (NR - 1);
    int gb = idx >> 9;
    int b = gb & (NB - 1);
    int g = gb >> 7;
    float a2 = 0.f, a5 = 0.f;
    if (f32) {
        const float* srow = (const float*)s + b * NTAG;
        const float* wb = (const float*)Wb + (long)g * NTAG * NR + r;
        const float* ub = (const float*)Ub + (long)g * NTAG * NR + r;
        for (int t = 0; t < NTAG; t++) {
            float sv = srow[t];
            a2 += sv * wb[(long)t * NR];
            a5 += sv * ub[(long)t * NR];
        }
    } else {
        const bf16* srow = (const bf16*)s + b * NTAG;
        const bf16* wb = (const bf16*)Wb + (long)g * NTAG * NR + r;
        const bf16* ub = (const bf16*)Ub + (long)g * NTAG * NR + r;
        for (int t = 0; t < NTAG; t++) {
            float sv = b2f(srow[t]);
            a2 += sv * b2f(wb[(long)t * NR]);
            a5 += sv * b2f(ub[(long)t * NR]);
        }
    }
    temp2[idx] = a2;
    temp5[idx] = a5;
}

// h,c init from layer 0 of h0,c0
__global__ __launch_bounds__(256) void k_init(const void* __restrict__ h0,
        const void* __restrict__ c0, const int* __restrict__ flagp,
        float* __restrict__ h, float* __restrict__ c) {
    int f32 = *flagp;
    int idx = blockIdx.x * 256 + threadIdx.x;      // over NB*NH
    h[idx] = ldin(h0, idx, f32);
    c[idx] = ldin(c0, idx, f32);
}

// t1m[g][m][r] = (sum_k xs[m][k]*Wa[g][k][r]) * temp2[g][b(m)][r]  (bf16 out)
// xs[m][k] gathered from emb via captions (teacher-forced, shifted), m = t*NB+b
__global__ __launch_bounds__(256) void k_g1(const int* __restrict__ captions,
        const void* __restrict__ emb, const void* __restrict__ Wa,
        const float* __restrict__ temp2, const int* __restrict__ flagp,
        bf16* __restrict__ t1m) {
    int f32 = *flagp;
    int g = blockIdx.z;
    __shared__ float As[16][65];
    __shared__ float Bs[16][65];
    int bm = blockIdx.y * 64, bn = blockIdx.x * 64;
    int tid = threadIdx.x, tx = tid & 15, ty = tid >> 4;
    float acc[4][4] = {};
    for (int k0 = 0; k0 < NE; k0 += 16) {
        #pragma unroll
        for (int i = 0; i < 4; i++) {
            int e = tid + i * 256; int ml = e >> 4, kl = e & 15;
            int m = bm + ml;
            int t = m >> 7, b = m & (NB - 1);
            float v = 0.f;
            if (t > 0) {
                int tok = captions[b * NT + (t - 1)];
                v = ldin(emb, (long)tok * NE + k0 + kl, f32);
            }
            As[kl][ml] = v;
        }
        #pragma unroll
        for (int i = 0; i < 4; i++) {
            int e = tid + i * 256; int kl = e >> 6, n = e & 63;
            Bs[kl][n] = ldin(Wa, (long)g * NE * NR + (long)(k0 + kl) * NR + bn + n, f32);
        }
        __syncthreads();
        #pragma unroll
        for (int k = 0; k < 16; k++) {
            float a0[4], b0[4];
            #pragma unroll
            for (int i = 0; i < 4; i++) a0[i] = As[k][ty + 16 * i];
            #pragma unroll
            for (int j = 0; j < 4; j++) b0[j] = Bs[k][tx + 16 * j];
            #pragma unroll
            for (int i = 0; i < 4; i++)
                #pragma unroll
                for (int j = 0; j < 4; j++) acc[i][j] += a0[i] * b0[j];
        }
        __syncthreads();
    }
    #pragma unroll
    for (int i = 0; i < 4; i++) {
        int m = bm + ty + 16 * i;
        int b = m & (NB - 1);
        #pragma unroll
        for (int j = 0; j < 4; j++) {
            int r = bn + tx + 16 * j;
            float sc = temp2[(long)((g * NB + b) << 9) + r];
            t1m[((long)g * NT * NB + m) * NR + r] = __float2bfloat16(acc[i][j] * sc);
        }
    }
}

// gx[g][m][h] = sum_r t1m[g][m][r] * Wc[g][r][h]  (bf16 out)
__global__ __launch_bounds__(256) void k_g2(const bf16* __restrict__ t1m,
        const void* __restrict__ Wc, const int* __restrict__ flagp,
        bf16* __restrict__ gx) {
    int f32 = *flagp;
    int g = blockIdx.z;
    __shared__ float As[16][65];
    __shared__ float Bs[16][65];
    int bm = blockIdx.y * 64, bn = blockIdx.x * 64;
    int tid = threadIdx.x, tx = tid & 15, ty = tid >> 4;
    float acc[4][4] = {};
    const bf16* A = t1m + (long)g * NT * NB * NR;
    for (int k0 = 0; k0 < NR; k0 += 16) {
        #pragma unroll
        for (int i = 0; i < 4; i++) {
            int e = tid + i * 256; int ml = e >> 4, kl = e & 15;
            As[kl][ml] = b2f(A[(long)(bm + ml) * NR + k0 + kl]);
        }
        #pragma unroll
        for (int i = 0; i < 4; i++) {
            int e = tid + i * 256; int kl = e >> 6, n = e & 63;
            Bs[kl][n] = ldin(Wc, (long)g * NR * NH + (long)(k0 + kl) * NH + bn + n, f32);
        }
        __syncthreads();
        #pragma unroll
        for (int k = 0; k < 16; k++) {
            float a0[4], b0[4];
            #pragma unroll
            for (int i = 0; i < 4; i++) a0[i] = As[k][ty + 16 * i];
            #pragma unroll
            for (int j = 0; j < 4; j++) b0[j] = Bs[k][tx + 16 * j];
            #pragma unroll
            for (int i = 0; i < 4; i++)
                #pragma unroll
                for (int j = 0; j < 4; j++) acc[i][j] += a0[i] * b0[j];
        }
        __syncthreads();
    }
    #pragma unroll
    for (int i = 0; i < 4; i++) {
        int m = bm + ty + 16 * i;
        #pragma unroll
        for (int j = 0; j < 4; j++) {
            gx[((long)g * NT * NB + m) * NH + bn + tx + 16 * j] = __float2bfloat16(acc[i][j]);
        }
    }
}

// temp6[g][b][r] = (sum_h h[b][h]*Ua[g][h][r]) * temp5[g][b][r]
__global__ __launch_bounds__(256) void k_hua(const float* __restrict__ h,
        const void* __restrict__ Ua, const float* __restrict__ temp5,
        const int* __restrict__ flagp, float* __restrict__ temp6) {
    int f32 = *flagp;
    int idx = blockIdx.x * 256 + threadIdx.x;      // over 4*NB*NR
    int r = idx & (NR - 1);
    int gb = idx >> 9;
    int b = gb & (NB - 1);
    int g = gb >> 7;
    const float* hrow = h + b * NH;
    float acc = 0.f;
    if (f32) {
        const float* u = (const float*)Ua + (long)g * NH * NR + r;
        #pragma unroll 4
        for (int k = 0; k < NH; k++) acc += hrow[k] * u[(long)k * NR];
    } else {
        const bf16* u = (const bf16*)Ua + (long)g * NH * NR + r;
        #pragma unroll 4
        for (int k = 0; k < NH; k++) acc += hrow[k] * b2f(u[(long)k * NR]);
    }
    temp6[idx] = acc * temp5[idx];
}

// pre[g] = gx[g][t][b][hh] + sum_r temp6[g][b][r]*Uc[g][r][hh] + bias[g][hh]; LSTM pointwise.
__global__ __launch_bounds__(256) void k_lstm(const float* __restrict__ temp6,
        const void* __restrict__ Uc, const bf16* __restrict__ gx,
        const void* __restrict__ bias, const int* __restrict__ flagp,
        float* __restrict__ h, float* __restrict__ c,
        bf16* __restrict__ hs_t, int t) {
    int f32 = *flagp;
    int idx = blockIdx.x * 256 + threadIdx.x;      // over NB*NH
    int hh = idx & (NH - 1);
    int b = idx >> 9;
    float pre[4];
    #pragma unroll
    for (int g = 0; g < 4; g++) {
        const float* t6 = temp6 + (long)(g * NB + b) * NR;
        float acc = 0.f;
        if (f32) {
            const float* u = (const float*)Uc + (long)g * NR * NH + hh;
            #pragma unroll 4
            for (int k = 0; k < NR; k++) acc += t6[k] * u[(long)k * NH];
        } else {
            const bf16* u = (const bf16*)Uc + (long)g * NR * NH + hh;
            #pragma unroll 4
            for (int k = 0; k < NR; k++) acc += t6[k] * b2f(u[(long)k * NH]);
        }
        pre[g] = acc + b2f(gx[((long)(g * NT + t) * NB + b) * NH + hh])
               + ldin(bias, g * NH + hh, f32);
    }
    float ig = 1.f / (1.f + expf(-pre[0]));
    float fg = 1.f / (1.f + expf(-pre[1]));
    float og = 1.f / (1.f + expf(-pre[2]));
    float ct = tanhf(pre[3]);
    float cn = fg * c[idx] + ig * ct;
    float hn = og * tanhf(cn);
    c[idx] = cn;
    h[idx] = hn;
    hs_t[idx] = __float2bfloat16(hn);
}

// out[b][t][v] = sum_h hs[(t*NB+b)][h]*Wout[h][v] + bout[v]
__global__ __launch_bounds__(256) void k_out(const bf16* __restrict__ A,
        const void* __restrict__ W, const void* __restrict__ bout,
        const int* __restrict__ flagp, void* __restrict__ outp) {
    int f32 = *flagp;
    __shared__ float As[16][65];
    __shared__ float Bs[16][65];
    int bm = blockIdx.y * 64, bn = blockIdx.x * 64;
    int tid = threadIdx.x, tx = tid & 15, ty = tid >> 4;
    float acc[4][4] = {};
    for (int k0 = 0; k0 < NH; k0 += 16) {
        #pragma unroll
        for (int i = 0; i < 4; i++) {
            int e = tid + i * 256; int ml = e >> 4, kl = e & 15;
            As[kl][ml] = b2f(A[(long)(bm + ml) * NH + k0 + kl]);
        }
        #pragma unroll
        for (int i = 0; i < 4; i++) {
            int e = tid + i * 256; int kl = e >> 6, n = e & 63;
            int gn = bn + n;
            Bs[kl][n] = (gn < NV) ? ldin(W, (long)(k0 + kl) * NV + gn, f32) : 0.f;
        }
        __syncthreads();
        #pragma unroll
        for (int k = 0; k < 16; k++) {
            float a0[4], b0[4];
            #pragma unroll
            for (int i = 0; i < 4; i++) a0[i] = As[k][ty + 16 * i];
            #pragma unroll
            for (int j = 0; j < 4; j++) b0[j] = Bs[k][tx + 16 * j];
            #pragma unroll
            for (int i = 0; i < 4; i++)
                #pragma unroll
                for (int j = 0; j < 4; j++) acc[i][j] += a0[i] * b0[j];
        }
        __syncthreads();
    }
    #pragma unroll
    for (int i = 0; i < 4; i++) {
        int m = bm + ty + 16 * i;
        int t = m >> 7;              // m = t*NB + b
        int b = m & (NB - 1);
        long orow = ((long)b * NT + t) * NV;
        #pragma unroll
        for (int j = 0; j < 4; j++) {
            int gn = bn + tx + 16 * j;
            if (gn < NV) {
                float v = acc[i][j] + ldin(bout, gn, f32);
                if (f32) ((float*)outp)[orow + gn] = v;
                else ((bf16*)outp)[orow + gn] = __float2bfloat16(v);
            }
        }
    }
}

extern "C" void kernel_launch(void* const* d_in, const int* in_sizes, int n_in,
                              void* d_out, int out_size, void* d_ws, size_t ws_size,
                              hipStream_t stream) {
    const int*  captions = (const int*)d_in[0];
    const void* s    = d_in[1];
    const void* h0   = d_in[2];
    const void* c0   = d_in[3];
    const void* Wa   = d_in[4];
    const void* Wb   = d_in[5];
    const void* Wc   = d_in[6];
    const void* Ua   = d_in[7];
    const void* Ub   = d_in[8];
    const void* Uc   = d_in[9];
    const void* bias = d_in[10];
    const void* emb  = d_in[11];
    const void* Wout = d_in[12];
    const void* bout = d_in[13];

    // workspace layout (~30.5 MB)
    char* w = (char*)d_ws;
    int*   flag  = (int*)w;                          // 256 B reserved
    float* temp2 = (float*)(w + 256);                // 4*NB*NR f32
    float* temp5 = temp2 + 4 * NB * NR;
    float* temp6 = temp5 + 4 * NB * NR;
    float* hbuf  = temp6 + 4 * NB * NR;              // NB*NH f32
    float* cbuf  = hbuf + NB * NH;
    bf16*  t1m   = (bf16*)(cbuf + NB * NH);          // 4*NT*NB*NR bf16
    bf16*  gx    = t1m + (long)4 * NT * NB * NR;     // 4*NT*NB*NH bf16
    bf16*  hs    = gx + (long)4 * NT * NB * NH;      // NT*NB*NH bf16

    dim3 blk(256);

    k_detect<<<1, blk, 0, stream>>>(emb, flag);
    k_tags<<<(4 * NB * NR) / 256, blk, 0, stream>>>(s, Wb, Ub, flag, temp2, temp5);
    k_init<<<(NB * NH) / 256, blk, 0, stream>>>(h0, c0, flag, hbuf, cbuf);

    // Hoisted input path: t1m = (emb-gather @ Wa[g]) * temp2[g];  gx = t1m @ Wc[g]
    k_g1<<<dim3(NR / 64, (NT * NB) / 64, 4), blk, 0, stream>>>(captions, emb, Wa, temp2, flag, t1m);
    k_g2<<<dim3(NH / 64, (NT * NB) / 64, 4), blk, 0, stream>>>(t1m, Wc, flag, gx);

    // Sequential recurrence
    for (int t = 0; t < NT; t++) {
        k_hua<<<(4 * NB * NR) / 256, blk, 0, stream>>>(hbuf, Ua, temp5, flag, temp6);
        k_lstm<<<(NB * NH) / 256, blk, 0, stream>>>(temp6, Uc, gx, bias, flag, hbuf, cbuf,
                                                    hs + (long)t * NB * NH, t);
    }

    // Output projection
    k_out<<<dim3((NV + 63) / 64, (NT * NB) / 64), blk, 0, stream>>>(hs, Wout, bout, flag, d_out);
}

// Round 3
// 3555.848 us; speedup vs baseline: 1.8735x; 1.8735x over previous
//
#include <hip/hip_runtime.h>
#include <hip/hip_bf16.h>
#include <math.h>

typedef unsigned short u16;
typedef short short8 __attribute__((ext_vector_type(8)));
typedef float floatx4 __attribute__((ext_vector_type(4)));

#define NB 128    // batch
#define NT 24     // time steps
#define NE 512    // embed dim
#define NH 512    // hidden dim
#define NR 512    // factor rank
#define NTAG 400  // tags
#define NV 20000  // vocab

__device__ __forceinline__ float bfu(u16 u) {
    unsigned x = ((unsigned)u) << 16;
    return __builtin_bit_cast(float, x);
}
__device__ __forceinline__ u16 f2b(float f) {
    unsigned u = __builtin_bit_cast(unsigned, f);
    unsigned r = (u + 0x7FFFu + ((u >> 16) & 1u)) >> 16;
    return (u16)r;
}
__device__ __forceinline__ float ldin(const void* p, long i, int f32) {
    return f32 ? ((const float*)p)[i] : bfu(((const u16*)p)[i]);
}

// Detect input dtype: fp32 data's low halves produce exponent-all-ones bf16
// patterns at p~1/256; true bf16 (scale 0.02) never does.
__global__ __launch_bounds__(256) void k_detect(const void* emb, int* flag) {
    __shared__ int cnt;
    if (threadIdx.x == 0) cnt = 0;
    __syncthreads();
    const u16* p = (const u16*)emb;
    int local = 0;
    for (int i = threadIdx.x; i < 65536; i += 256) {
        if ((p[i] & 0x7F80) == 0x7F80) local++;
    }
    atomicAdd(&cnt, local);
    __syncthreads();
    if (threadIdx.x == 0) *flag = (cnt > 4) ? 1 : 0;
}

// temp2[g][b][r] = sum_t s[b][t]*Wb[g][t][r] ; temp5 likewise with Ub
__global__ __launch_bounds__(256) void k_tags(const void* __restrict__ s,
        const void* __restrict__ Wb, const void* __restrict__ Ub,
        const int* __restrict__ flagp, float* __restrict__ temp2, float* __restrict__ temp5) {
    int f32 = *flagp;
    int idx = blockIdx.x * 256 + threadIdx.x;      // over 4*NB*NR
    int r = idx & (NR - 1);
    int gb = idx >> 9;
    int b = gb & (NB - 1);
    int g = gb >> 7;
    float a2 = 0.f, a5 = 0.f;
    if (f32) {
        const float* srow = (const float*)s + b * NTAG;
        const float* wb = (const float*)Wb + (long)g * NTAG * NR + r;
        const float* ub = (const float*)Ub + (long)g * NTAG * NR + r;
        for (int t = 0; t < NTAG; t++) {
            float sv = srow[t];
            a2 += sv * wb[(long)t * NR];
            a5 += sv * ub[(long)t * NR];
        }
    } else {
        const u16* srow = (const u16*)s + b * NTAG;
        const u16* wb = (const u16*)Wb + (long)g * NTAG * NR + r;
        const u16* ub = (const u16*)Ub + (long)g * NTAG * NR + r;
        for (int t = 0; t < NTAG; t++) {
            float sv = bfu(srow[t]);
            a2 += sv * bfu(wb[(long)t * NR]);
            a5 += sv * bfu(ub[(long)t * NR]);
        }
    }
    temp2[idx] = a2;
    temp5[idx] = a5;
}

// Tiled transpose to bf16: out[g][j][i] = in[g][i][j], 512x512 per gate.
// z = which*4 + g: which 0 -> Ua->UaT, which 1 -> Uc->UcT.
__global__ __launch_bounds__(256) void k_tr(const void* __restrict__ Ua,
        const void* __restrict__ Uc, const int* __restrict__ flagp,
        u16* __restrict__ UaT, u16* __restrict__ UcT) {
    int f32 = *flagp;
    int z = blockIdx.z;
    int which = z >> 2, g = z & 3;
    const void* src = which ? Uc : Ua;
    u16* dst = which ? UcT : UaT;
    __shared__ u16 tile[64][65];
    int i0 = blockIdx.x * 64;   // input row block
    int j0 = blockIdx.y * 64;   // input col block
    int t = threadIdx.x;
    int il = t >> 2, js = (t & 3) * 16;
    long base = ((long)g * 512 + i0 + il) * 512 + j0 + js;
    if (f32) {
        const float* q = (const float*)src + base;
        #pragma unroll
        for (int j = 0; j < 16; j++) tile[il][js + j] = f2b(q[j]);
    } else {
        const u16* q = (const u16*)src + base;
        #pragma unroll
        for (int j = 0; j < 16; j++) tile[il][js + j] = q[j];
    }
    __syncthreads();
    int jl = t >> 2, is = (t & 3) * 16;
    long ob = ((long)g * 512 + j0 + jl) * 512 + i0 + is;
    #pragma unroll
    for (int i = 0; i < 16; i++) dst[ob + i] = tile[is + i][jl];
}

// MFMA GEMM, block tile 64(M) x 128(N), K=512, 256 threads (4 waves).
// MODE 0: A = emb-gather (flag dtype), B = Wa[g] (flag), epi: *temp2 -> t1m bf16
// MODE 1: A = t1m[g] bf16, B = Wc[g] (flag), epi: plain -> gx bf16
// MODE 2: A = hs bf16, B = Wout (flag), epi: +bout, swizzle (t,b)->(b,t), guard n<NV
template<int MODE>
__global__ __launch_bounds__(256) void k_mfma(const void* __restrict__ Asrc,
        const void* __restrict__ Bsrc, void* __restrict__ dst,
        const int* __restrict__ captions, const float* __restrict__ temp2,
        const void* __restrict__ bout, const int* __restrict__ flagp) {
    const int f32 = *flagp;
    const int bm = blockIdx.x * 64;
    const int bn = blockIdx.y * 128;
    const int g = blockIdx.z;
    const int NN = (MODE == 2) ? NV : NR;
    const int ldb = (MODE == 2) ? NV : NR;
    __shared__ __align__(16) u16 As[64 * 40];
    __shared__ __align__(16) u16 Bs[32 * 132];
    const int tid = threadIdx.x;
    const int sam = tid >> 2, sak = (tid & 3) * 8;      // A staging: row, k-offset
    const int sbk = tid >> 3, sbn = (tid & 7) * 16;     // B staging: k-row, n-offset
    long arow = 0;
    int azero = 0;
    if (MODE == 0) {
        int mg = bm + sam, tt = mg >> 7, bb = mg & (NB - 1);
        if (tt == 0) azero = 1;
        else arow = (long)captions[bb * NT + tt - 1] * NE;
    } else if (MODE == 1) {
        arow = ((long)g * NT * NB + bm + sam) * NR;
    } else {
        arow = (long)(bm + sam) * NH;
    }
    long bbase;
    if (MODE == 2) bbase = bn + sbn;
    else bbase = (long)g * 512 * 512 + bn + sbn;
    const int bguard = (MODE == 2) && (bn + 128 > NN);

    const int wv = tid >> 6, ln = tid & 63;
    const int q = ln >> 4, l15 = ln & 15;
    floatx4 acc[4][2];
    #pragma unroll
    for (int i = 0; i < 4; i++)
        #pragma unroll
        for (int j = 0; j < 2; j++)
            #pragma unroll
            for (int r = 0; r < 4; r++) acc[i][j][r] = 0.f;

    for (int k0 = 0; k0 < 512; k0 += 32) {
        // ---- stage A (8 elems/thread) ----
        u16 ta[8] __attribute__((aligned(16)));
        if (MODE == 0) {
            if (azero) {
                #pragma unroll
                for (int j = 0; j < 8; j++) ta[j] = 0;
            } else if (f32) {
                const float* qa = (const float*)Asrc + arow + k0 + sak;
                #pragma unroll
                for (int j = 0; j < 8; j++) ta[j] = f2b(qa[j]);
            } else {
                *(uint4*)ta = *(const uint4*)((const u16*)Asrc + arow + k0 + sak);
            }
        } else {
            *(uint4*)ta = *(const uint4*)((const u16*)Asrc + arow + k0 + sak);
        }
        *(uint4*)&As[sam * 40 + sak] = *(uint4*)ta;
        // ---- stage B (16 elems/thread, natural [k][n]) ----
        u16 tb[16] __attribute__((aligned(16)));
        long be = bbase + (long)(k0 + sbk) * ldb;
        if (!bguard) {
            if (f32) {
                const float* qb = (const float*)Bsrc + be;
                #pragma unroll
                for (int j = 0; j < 16; j++) tb[j] = f2b(qb[j]);
            } else {
                *(uint4*)tb = *(const uint4*)((const u16*)Bsrc + be);
                *(uint4*)(tb + 8) = *(const uint4*)((const u16*)Bsrc + be + 8);
            }
        } else {
            #pragma unroll
            for (int j = 0; j < 16; j++) {
                int n = bn + sbn + j;
                tb[j] = (n < NN) ? (f32 ? f2b(((const float*)Bsrc)[be + j])
                                        : ((const u16*)Bsrc)[be + j]) : (u16)0;
            }
        }
        *(uint2*)&Bs[sbk * 132 + sbn]      = *(uint2*)tb;
        *(uint2*)&Bs[sbk * 132 + sbn + 4]  = *(uint2*)(tb + 4);
        *(uint2*)&Bs[sbk * 132 + sbn + 8]  = *(uint2*)(tb + 8);
        *(uint2*)&Bs[sbk * 132 + sbn + 12] = *(uint2*)(tb + 12);
        __syncthreads();
        // ---- fragments + MFMA ----
        short8 af[4];
        #pragma unroll
        for (int mi = 0; mi < 4; mi++)
            af[mi] = *(const short8*)&As[(mi * 16 + l15) * 40 + q * 8];
        #pragma unroll
        for (int ni = 0; ni < 2; ni++) {
            union { u16 u[8]; short8 v; } bu;
            int n = wv * 32 + ni * 16 + l15;
            #pragma unroll
            for (int j = 0; j < 8; j++) bu.u[j] = Bs[(q * 8 + j) * 132 + n];
            #pragma unroll
            for (int mi = 0; mi < 4; mi++)
                acc[mi][ni] = __builtin_amdgcn_mfma_f32_16x16x32_bf16(af[mi], bu.v, acc[mi][ni], 0, 0, 0);
        }
        __syncthreads();
    }
    // ---- epilogue ----
    #pragma unroll
    for (int mi = 0; mi < 4; mi++) {
        #pragma unroll
        for (int ni = 0; ni < 2; ni++) {
            int n = bn + wv * 32 + ni * 16 + l15;
            #pragma unroll
            for (int r = 0; r < 4; r++) {
                int m = bm + mi * 16 + q * 4 + r;
                float v = acc[mi][ni][r];
                if (MODE == 0) {
                    int bb = m & (NB - 1);
                    v *= temp2[((long)g * NB + bb) * NR + n];
                    ((u16*)dst)[((long)g * NT * NB + m) * NR + n] = f2b(v);
                } else if (MODE == 1) {
                    ((u16*)dst)[((long)g * NT * NB + m) * NR + n] = f2b(v);
                } else {
                    if (n < NV) {
                        int tt = m >> 7, bb = m & (NB - 1);
                        float o = v + ldin(bout, n, f32);
                        long oi = ((long)bb * NT + tt) * NV + n;
                        if (f32) ((float*)dst)[oi] = o;
                        else ((u16*)dst)[oi] = f2b(o);
                    }
                }
            }
        }
    }
}

// Whole recurrence in one kernel: block = one batch row b, 1024 threads, 24 steps.
// Thread handles gates (g, g+2) at index rr for both phases.
__global__ __launch_bounds__(1024) void k_rec(const u16* __restrict__ UaT,
        const u16* __restrict__ UcT, const float* __restrict__ temp5,
        const u16* __restrict__ gx, const void* __restrict__ bias,
        const void* __restrict__ h0, const void* __restrict__ c0,
        const int* __restrict__ flagp, u16* __restrict__ hs) {
    const int f32 = *flagp;
    const int b = blockIdx.x;
    __shared__ __align__(16) u16 hb[NH];
    __shared__ __align__(16) u16 t6[4 * NR];
    __shared__ float cl[NH];
    __shared__ float pre[4 * NH];
    const int tid = threadIdx.x;
    if (tid < NH) {
        hb[tid] = f2b(ldin(h0, (long)b * NH + tid, f32));
        cl[tid] = ldin(c0, (long)b * NH + tid, f32);
    }
    const int g = tid >> 9;       // 0 or 1 (second output is gate g+2)
    const int rr = tid & 511;
    const uint4* rA0 = (const uint4*)(UaT + ((long)g * NR + rr) * NH);
    const uint4* rA1 = (const uint4*)(UaT + ((long)(g + 2) * NR + rr) * NH);
    const uint4* rB0 = (const uint4*)(UcT + ((long)g * NH + rr) * NR);
    const uint4* rB1 = (const uint4*)(UcT + ((long)(g + 2) * NH + rr) * NR);
    const float t5a = temp5[((long)g * NB + b) * NR + rr];
    const float t5b = temp5[((long)(g + 2) * NB + b) * NR + rr];
    const float bia = ldin(bias, g * NH + rr, f32);
    const float bib = ldin(bias, (g + 2) * NH + rr, f32);
    __syncthreads();
    for (int t = 0; t < NT; t++) {
        // phase A: temp6[g][rr] = (h . UaT[g][rr]) * temp5
        float a0 = 0.f, a1 = 0.f;
        const uint4* hv4 = (const uint4*)hb;
        #pragma unroll 4
        for (int kk = 0; kk < 64; kk++) {
            uint4 h4 = hv4[kk], w0 = rA0[kk], w1 = rA1[kk];
            const unsigned* hp = (const unsigned*)&h4;
            const unsigned* p0 = (const unsigned*)&w0;
            const unsigned* p1 = (const unsigned*)&w1;
            #pragma unroll
            for (int i = 0; i < 4; i++) {
                float hl = __builtin_bit_cast(float, hp[i] << 16);
                float hh = __builtin_bit_cast(float, hp[i] & 0xFFFF0000u);
                a0 = fmaf(__builtin_bit_cast(float, p0[i] << 16), hl, a0);
                a0 = fmaf(__builtin_bit_cast(float, p0[i] & 0xFFFF0000u), hh, a0);
                a1 = fmaf(__builtin_bit_cast(float, p1[i] << 16), hl, a1);
                a1 = fmaf(__builtin_bit_cast(float, p1[i] & 0xFFFF0000u), hh, a1);
            }
        }
        t6[g * NR + rr] = f2b(a0 * t5a);
        t6[(g + 2) * NR + rr] = f2b(a1 * t5b);
        __syncthreads();
        // phase B: pre[g][rr] = (temp6[g] . UcT[g][rr]) + gx + bias
        float s0 = 0.f, s1 = 0.f;
        const uint4* tv0 = (const uint4*)(t6 + g * NR);
        const uint4* tv1 = (const uint4*)(t6 + (g + 2) * NR);
        #pragma unroll 4
        for (int kk = 0; kk < 64; kk++) {
            uint4 x0 = tv0[kk], x1 = tv1[kk], w0 = rB0[kk], w1 = rB1[kk];
            const unsigned* a0p = (const unsigned*)&x0;
            const unsigned* a1p = (const unsigned*)&x1;
            const unsigned* p0 = (const unsigned*)&w0;
            const unsigned* p1 = (const unsigned*)&w1;
            #pragma unroll
            for (int i = 0; i < 4; i++) {
                s0 = fmaf(__builtin_bit_cast(float, p0[i] << 16),
                          __builtin_bit_cast(float, a0p[i] << 16), s0);
                s0 = fmaf(__builtin_bit_cast(float, p0[i] & 0xFFFF0000u),
                          __builtin_bit_cast(float, a0p[i] & 0xFFFF0000u), s0);
                s1 = fmaf(__builtin_bit_cast(float, p1[i] << 16),
                          __builtin_bit_cast(float, a1p[i] << 16), s1);
                s1 = fmaf(__builtin_bit_cast(float, p1[i] & 0xFFFF0000u),
                          __builtin_bit_cast(float, a1p[i] & 0xFFFF0000u), s1);
            }
        }
        long gi0 = (((long)g * NT + t) * NB + b) * NH + rr;
        long gi1 = (((long)(g + 2) * NT + t) * NB + b) * NH + rr;
        pre[g * NH + rr] = s0 + bfu(gx[gi0]) + bia;
        pre[(g + 2) * NH + rr] = s1 + bfu(gx[gi1]) + bib;
        __syncthreads();
        // pointwise LSTM
        if (tid < NH) {
            float ig = 1.f / (1.f + expf(-pre[tid]));
            float fg = 1.f / (1.f + expf(-pre[NH + tid]));
            float og = 1.f / (1.f + expf(-pre[2 * NH + tid]));
            float ct = tanhf(pre[3 * NH + tid]);
            float cn = fg * cl[tid] + ig * ct;
            float hn = og * tanhf(cn);
            cl[tid] = cn;
            u16 hv = f2b(hn);
            hb[tid] = hv;
            hs[((long)t * NB + b) * NH + tid] = hv;
        }
        __syncthreads();
    }
}

extern "C" void kernel_launch(void* const* d_in, const int* in_sizes, int n_in,
                              void* d_out, int out_size, void* d_ws, size_t ws_size,
                              hipStream_t stream) {
    const int* captions = (const int*)d_in[0];
    const void* s    = d_in[1];
    const void* h0   = d_in[2];
    const void* c0   = d_in[3];
    const void* Wa   = d_in[4];
    const void* Wb   = d_in[5];
    const void* Wc   = d_in[6];
    const void* Ua   = d_in[7];
    const void* Ub   = d_in[8];
    const void* Uc   = d_in[9];
    const void* bias = d_in[10];
    const void* emb  = d_in[11];
    const void* Wout = d_in[12];
    const void* bout = d_in[13];

    // workspace (~31.5 MB)
    char* w = (char*)d_ws;
    int*   flag  = (int*)w;                                  // 256 B
    float* temp2 = (float*)(w + 256);                        // 1 MB
    float* temp5 = temp2 + 4 * NB * NR;                      // 1 MB
    u16*   UaT   = (u16*)(temp5 + 4 * NB * NR);              // 2 MB bf16
    u16*   UcT   = UaT + 4 * 512 * 512;                      // 2 MB bf16
    u16*   t1m   = UcT + 4 * 512 * 512;                      // 12.6 MB bf16
    u16*   gx    = t1m + (long)4 * NT * NB * NR;             // 12.6 MB bf16
    u16*   hs    = t1m;  // alias: t1m dead after k_mfma<1>

    dim3 blk(256);
    k_detect<<<1, blk, 0, stream>>>(emb, flag);
    k_tags<<<(4 * NB * NR) / 256, blk, 0, stream>>>(s, Wb, Ub, flag, temp2, temp5);
    k_tr<<<dim3(8, 8, 8), blk, 0, stream>>>(Ua, Uc, flag, UaT, UcT);

    // hoisted input path (MFMA)
    k_mfma<0><<<dim3(48, 4, 4), blk, 0, stream>>>(emb, Wa, t1m, captions, temp2, nullptr, flag);
    k_mfma<1><<<dim3(48, 4, 4), blk, 0, stream>>>(t1m, Wc, gx, nullptr, nullptr, nullptr, flag);

    // fused recurrence: one launch, one block per batch row
    k_rec<<<128, 1024, 0, stream>>>(UaT, UcT, temp5, gx, bias, h0, c0, flag, hs);

    // output projection (MFMA), grid.x = M-tiles so consecutive blocks share W strip in L2
    k_mfma<2><<<dim3(48, 157, 1), blk, 0, stream>>>(hs, Wout, d_out, nullptr, nullptr, bout, flag);
}